// Round 1
// baseline (238.441 us; speedup 1.0000x reference)
//
#include <hip/hip_runtime.h>
#include <math.h>

// ---------------------------------------------------------------------------
// Problem: B=64 batches. a_p = a@W1^T + b1 [64,1024]; b_p = b@W2^T + b2.
// cost[b,i,j] = (a_p[b,i]-b_p[b,j])^2 ; DTW DP R[i,j]=cost+min(diag,up,left);
// out[b] = R[1023,1023].
// ---------------------------------------------------------------------------

#define L 1024
#define BATCH 64

// ---------------- GEMM: out[b,i] = sum_k X[b,k]*W[i,k] + bias[i] -----------
// grid.x = 128: blocks [0,64) compute a_p (X=a,W=W1), [64,128) compute b_p.
// Each block: 64 b x 16 i tile, K chunked by 32, staged through LDS.
__global__ __launch_bounds__(256) void proj_kernel(
    const float* __restrict__ a, const float* __restrict__ b,
    const float* __restrict__ W1, const float* __restrict__ b1,
    const float* __restrict__ W2, const float* __restrict__ b2,
    float* __restrict__ ap, float* __restrict__ bp) {
  int blk = blockIdx.x;
  const float* X;
  const float* W;
  const float* bias;
  float* out;
  int i0;
  if (blk < 64) {
    X = a; W = W1; bias = b1; out = ap; i0 = blk * 16;
  } else {
    X = b; W = W2; bias = b2; out = bp; i0 = (blk - 64) * 16;
  }

  __shared__ float a_s[64][33];   // 64 b x 32 k, +1 pad
  __shared__ float w_s[16][33];   // 16 i x 32 k

  int tid = threadIdx.x;
  int lane_b = tid & 63;   // batch index this thread accumulates for
  int iq = tid >> 6;       // wave id 0..3 -> handles i_local = iq*4 + m

  float acc[4] = {0.f, 0.f, 0.f, 0.f};

  for (int k0 = 0; k0 < L; k0 += 32) {
    // stage a tile: 64 rows x 32 k = 2048 floats; 8 per thread (2x float4)
    {
      int row = tid >> 2;            // 0..63
      int kl = (tid & 3) * 8;        // 0,8,16,24
      const float4* src = reinterpret_cast<const float4*>(&X[row * L + k0 + kl]);
      float4 v0 = src[0];
      float4 v1 = src[1];
      a_s[row][kl + 0] = v0.x; a_s[row][kl + 1] = v0.y;
      a_s[row][kl + 2] = v0.z; a_s[row][kl + 3] = v0.w;
      a_s[row][kl + 4] = v1.x; a_s[row][kl + 5] = v1.y;
      a_s[row][kl + 6] = v1.z; a_s[row][kl + 7] = v1.w;
    }
    // stage w tile: 16 rows x 32 k = 512 floats; 2 per thread
    {
      int row = tid >> 4;            // 0..15
      int kl = (tid & 15) * 2;
      float2 v = *reinterpret_cast<const float2*>(&W[(i0 + row) * L + k0 + kl]);
      w_s[row][kl] = v.x;
      w_s[row][kl + 1] = v.y;
    }
    __syncthreads();
    #pragma unroll 8
    for (int kl = 0; kl < 32; ++kl) {
      float av = a_s[lane_b][kl];
      #pragma unroll
      for (int m = 0; m < 4; ++m) {
        acc[m] += av * w_s[iq * 4 + m][kl];
      }
    }
    __syncthreads();
  }

  #pragma unroll
  for (int m = 0; m < 4; ++m) {
    int i = i0 + iq * 4 + m;
    out[lane_b * L + i] = acc[m] + bias[i];
  }
}

// ---------------- DTW: one wave per batch, systolic over lanes -------------
// Lane t owns columns [16t, 16t+16). At step s, lane t processes row i=s-t.
// prev[m] holds R[i-1, 16t+m]. Boundary x[16t-1] arrives via shfl_up from
// lane t-1 (produced one step earlier); the previous step's boundary is the
// diagonal R[i-1,16t-1].
__global__ __launch_bounds__(64) void dtw_kernel(const float* __restrict__ ap,
                                                 const float* __restrict__ bp,
                                                 float* __restrict__ out) {
  const int b = blockIdx.x;
  const int t = threadIdx.x;  // lane 0..63
  const float INF = INFINITY;

  __shared__ float ap_s[L];
  #pragma unroll
  for (int k = 0; k < L / 64; ++k) ap_s[t + 64 * k] = ap[b * L + t + 64 * k];

  float bpv[16];
  float prev[16];
  #pragma unroll
  for (int m = 0; m < 16; ++m) {
    bpv[m] = bp[b * L + t * 16 + m];
    prev[m] = INF;
  }
  __syncthreads();

  float right = INF;      // my x[15] of the row I last processed
  float prev_left = INF;  // R[i-1, 16t-1]

  for (int s = 0; s < L + 63; ++s) {
    float left = __shfl_up(right, 1);
    int i = s - t;
    if (t == 0) left = (i == 0) ? 0.f : INF;
    if (i >= 0 && i < L) {
      float apv = ap_s[i];
      float c[16];
      #pragma unroll
      for (int m = 0; m < 16; ++m) {
        float d = apv - bpv[m];
        c[m] = d * d;
      }
      float x = left;
      float dprev = (t == 0) ? INF : prev_left;
      #pragma unroll
      for (int m = 0; m < 16; ++m) {
        float cur = prev[m];
        float best = fminf(fminf(cur, dprev), x);
        x = best + c[m];
        dprev = cur;
        prev[m] = x;
      }
      prev_left = left;
      right = x;
    }
  }

  if (t == 63) out[b] = right;  // R[1023,1023]
}

extern "C" void kernel_launch(void* const* d_in, const int* in_sizes, int n_in,
                              void* d_out, int out_size, void* d_ws, size_t ws_size,
                              hipStream_t stream) {
  const float* a  = (const float*)d_in[0];
  const float* b  = (const float*)d_in[1];
  const float* W1 = (const float*)d_in[2];
  const float* b1 = (const float*)d_in[3];
  const float* W2 = (const float*)d_in[4];
  const float* b2 = (const float*)d_in[5];
  float* out = (float*)d_out;

  float* ap = (float*)d_ws;
  float* bp = ap + BATCH * L;

  proj_kernel<<<128, 256, 0, stream>>>(a, b, W1, b1, W2, b2, ap, bp);
  dtw_kernel<<<BATCH, 64, 0, stream>>>(ap, bp, out);
}

// Round 2
// 204.013 us; speedup vs baseline: 1.1688x; 1.1688x over previous
//
#include <hip/hip_runtime.h>
#include <math.h>

// ---------------------------------------------------------------------------
// Problem: B=64 batches. a_p = a@W1^T + b1 [64,1024]; b_p = b@W2^T + b2.
// cost[b,i,j] = (a_p[b,i]-b_p[b,j])^2 ; DTW DP R[i,j]=cost+min(diag,up,left);
// out[b] = R[1023,1023].
// ---------------------------------------------------------------------------

#define L 1024
#define BATCH 64

// ---------------- GEMM: out[b,i] = sum_k X[b,k]*W[i,k] + bias[i] -----------
__global__ __launch_bounds__(256) void proj_kernel(
    const float* __restrict__ a, const float* __restrict__ b,
    const float* __restrict__ W1, const float* __restrict__ b1,
    const float* __restrict__ W2, const float* __restrict__ b2,
    float* __restrict__ ap, float* __restrict__ bp) {
  int blk = blockIdx.x;
  const float* X;
  const float* W;
  const float* bias;
  float* out;
  int i0;
  if (blk < 64) {
    X = a; W = W1; bias = b1; out = ap; i0 = blk * 16;
  } else {
    X = b; W = W2; bias = b2; out = bp; i0 = (blk - 64) * 16;
  }

  __shared__ float a_s[64][33];
  __shared__ float w_s[16][33];

  int tid = threadIdx.x;
  int lane_b = tid & 63;
  int iq = tid >> 6;

  float acc[4] = {0.f, 0.f, 0.f, 0.f};

  for (int k0 = 0; k0 < L; k0 += 32) {
    {
      int row = tid >> 2;
      int kl = (tid & 3) * 8;
      const float4* src = reinterpret_cast<const float4*>(&X[row * L + k0 + kl]);
      float4 v0 = src[0];
      float4 v1 = src[1];
      a_s[row][kl + 0] = v0.x; a_s[row][kl + 1] = v0.y;
      a_s[row][kl + 2] = v0.z; a_s[row][kl + 3] = v0.w;
      a_s[row][kl + 4] = v1.x; a_s[row][kl + 5] = v1.y;
      a_s[row][kl + 6] = v1.z; a_s[row][kl + 7] = v1.w;
    }
    {
      int row = tid >> 4;
      int kl = (tid & 15) * 2;
      float2 v = *reinterpret_cast<const float2*>(&W[(i0 + row) * L + k0 + kl]);
      w_s[row][kl] = v.x;
      w_s[row][kl + 1] = v.y;
    }
    __syncthreads();
    #pragma unroll 8
    for (int kl = 0; kl < 32; ++kl) {
      float av = a_s[lane_b][kl];
      #pragma unroll
      for (int m = 0; m < 4; ++m) {
        acc[m] += av * w_s[iq * 4 + m][kl];
      }
    }
    __syncthreads();
  }

  #pragma unroll
  for (int m = 0; m < 4; ++m) {
    int i = i0 + iq * 4 + m;
    out[lane_b * L + i] = acc[m] + bias[i];
  }
}

// ---------------- DTW: one wave per batch, systolic over lanes -------------
// Lane t owns columns [16t, 16t+16). At step s, lane t processes row i=s-t.
// Cross-lane boundary moves lane t-1 -> t via DPP wave_shr:1 (whole-wave
// shift, ~VALU latency) instead of ds_bpermute (~120 cyc).

__device__ __forceinline__ float wave_shr1(float v, float fill) {
  // dpp_ctrl 0x138 = wave_shr:1 (lane i reads lane i-1); lane 0 takes `fill`
  // via the `old` operand (bound_ctrl=false -> invalid source keeps old).
  int r = __builtin_amdgcn_update_dpp(__float_as_int(fill), __float_as_int(v),
                                      0x138, 0xf, 0xf, false);
  return __int_as_float(r);
}

__global__ __launch_bounds__(64) void dtw_kernel(const float* __restrict__ ap,
                                                 const float* __restrict__ bp,
                                                 float* __restrict__ out) {
  const int b = blockIdx.x;
  const int t = threadIdx.x;  // lane 0..63
  const float INF = INFINITY;

  __shared__ float ap_s[L];
  #pragma unroll
  for (int k = 0; k < L / 64; ++k) ap_s[t + 64 * k] = ap[b * L + t + 64 * k];

  float bpv[16];
  float prev[16];
  #pragma unroll
  for (int m = 0; m < 16; ++m) {
    bpv[m] = bp[b * L + t * 16 + m];
    prev[m] = INF;
  }
  __syncthreads();

  float right = INF;      // my x[15] of the row I last processed
  float prev_left = INF;  // R[i-1, 16t-1]
  float apv_pf = ap_s[0]; // prefetched a_p value for my next active row

  // One systolic step. CHECK: predicate lanes whose row index is outside
  // [0, L). In the steady phase all lanes are in range -> no predicate.
#define DTW_STEP(s, CHECK)                                                   \
  {                                                                          \
    float left = wave_shr1(right, INF);                                      \
    int i = (s) - t;                                                         \
    float apv = apv_pf;                                                      \
    int nidx = (s) + 1 - t;                                                  \
    nidx = nidx < 0 ? 0 : (nidx > L - 1 ? L - 1 : nidx);                     \
    apv_pf = ap_s[nidx];                                                     \
    if (t == 0) left = (i == 0) ? 0.f : INF;                                 \
    if (!(CHECK) || (i >= 0 && i < L)) {                                     \
      float d[16];                                                           \
      _Pragma("unroll")                                                      \
      for (int m = 0; m < 16; ++m) d[m] = apv - bpv[m];                      \
      float x = left;                                                        \
      float dprev = (t == 0) ? INF : prev_left;                              \
      _Pragma("unroll")                                                      \
      for (int m = 0; m < 16; ++m) {                                         \
        float cur = prev[m];                                                 \
        float best = fminf(fminf(cur, dprev), x);                            \
        x = __builtin_fmaf(d[m], d[m], best);                                \
        dprev = cur;                                                         \
        prev[m] = x;                                                         \
      }                                                                      \
      prev_left = left;                                                      \
      right = x;                                                             \
    }                                                                        \
  }

  // Phase 1: ramp-up (some lanes not yet started)
  for (int s = 0; s < 63; ++s) DTW_STEP(s, true);
  // Phase 2: steady state — all 64 lanes in range, no predicate
  for (int s = 63; s < L; ++s) DTW_STEP(s, false);
  // Phase 3: drain (high lanes still finishing)
  for (int s = L; s < L + 63; ++s) DTW_STEP(s, true);
#undef DTW_STEP

  if (t == 63) out[b] = right;  // R[1023,1023]
}

extern "C" void kernel_launch(void* const* d_in, const int* in_sizes, int n_in,
                              void* d_out, int out_size, void* d_ws, size_t ws_size,
                              hipStream_t stream) {
  const float* a  = (const float*)d_in[0];
  const float* b  = (const float*)d_in[1];
  const float* W1 = (const float*)d_in[2];
  const float* b1 = (const float*)d_in[3];
  const float* W2 = (const float*)d_in[4];
  const float* b2 = (const float*)d_in[5];
  float* out = (float*)d_out;

  float* ap = (float*)d_ws;
  float* bp = ap + BATCH * L;

  proj_kernel<<<128, 256, 0, stream>>>(a, b, W1, b1, W2, b2, ap, bp);
  dtw_kernel<<<BATCH, 64, 0, stream>>>(ap, bp, out);
}

// Round 3
// 172.891 us; speedup vs baseline: 1.3791x; 1.1800x over previous
//
#include <hip/hip_runtime.h>
#include <math.h>

// ---------------------------------------------------------------------------
// Problem: B=64 batches. a_p = a@W1^T + b1 [64,1024]; b_p = b@W2^T + b2.
// cost[b,i,j] = (a_p[b,i]-b_p[b,j])^2 ; DTW DP R[i,j]=cost+min(diag,up,left);
// out[b] = R[1023,1023].
// ---------------------------------------------------------------------------

#define L 1024
#define BATCH 64

// ---------------- GEMM: out[b,i] = sum_k X[b,k]*W[i,k] + bias[i] -----------
__global__ __launch_bounds__(256) void proj_kernel(
    const float* __restrict__ a, const float* __restrict__ b,
    const float* __restrict__ W1, const float* __restrict__ b1,
    const float* __restrict__ W2, const float* __restrict__ b2,
    float* __restrict__ ap, float* __restrict__ bp) {
  int blk = blockIdx.x;
  const float* X;
  const float* W;
  const float* bias;
  float* out;
  int i0;
  if (blk < 64) {
    X = a; W = W1; bias = b1; out = ap; i0 = blk * 16;
  } else {
    X = b; W = W2; bias = b2; out = bp; i0 = (blk - 64) * 16;
  }

  __shared__ float a_s[64][33];
  __shared__ float w_s[16][33];

  int tid = threadIdx.x;
  int lane_b = tid & 63;
  int iq = tid >> 6;

  float acc[4] = {0.f, 0.f, 0.f, 0.f};

  for (int k0 = 0; k0 < L; k0 += 32) {
    {
      int row = tid >> 2;
      int kl = (tid & 3) * 8;
      const float4* src = reinterpret_cast<const float4*>(&X[row * L + k0 + kl]);
      float4 v0 = src[0];
      float4 v1 = src[1];
      a_s[row][kl + 0] = v0.x; a_s[row][kl + 1] = v0.y;
      a_s[row][kl + 2] = v0.z; a_s[row][kl + 3] = v0.w;
      a_s[row][kl + 4] = v1.x; a_s[row][kl + 5] = v1.y;
      a_s[row][kl + 6] = v1.z; a_s[row][kl + 7] = v1.w;
    }
    {
      int row = tid >> 4;
      int kl = (tid & 15) * 2;
      float2 v = *reinterpret_cast<const float2*>(&W[(i0 + row) * L + k0 + kl]);
      w_s[row][kl] = v.x;
      w_s[row][kl + 1] = v.y;
    }
    __syncthreads();
    #pragma unroll 8
    for (int kl = 0; kl < 32; ++kl) {
      float av = a_s[lane_b][kl];
      #pragma unroll
      for (int m = 0; m < 4; ++m) {
        acc[m] += av * w_s[iq * 4 + m][kl];
      }
    }
    __syncthreads();
  }

  #pragma unroll
  for (int m = 0; m < 4; ++m) {
    int i = i0 + iq * 4 + m;
    out[lane_b * L + i] = acc[m] + bias[i];
  }
}

// ---------------- DTW: one wave per batch, systolic over lanes -------------
// Lane t owns columns [16t, 16t+16). At step s, lane t processes row i=s-t.
// Cross-lane boundary moves lane t-1 -> t via DPP wave_shr:1.
// Steady state (s in [64,1024)) has NO predicates, NO lane-0 fixups, and the
// ap value arrives through a depth-2 register prefetch queue from padded LDS.

__device__ __forceinline__ float wave_shr1(float v, float fill) {
  // dpp_ctrl 0x138 = wave_shr:1 (lane i reads lane i-1); lane 0 keeps `old`
  // (bound_ctrl=false -> invalid source keeps old operand).
  int r = __builtin_amdgcn_update_dpp(__float_as_int(fill), __float_as_int(v),
                                      0x138, 0xf, 0xf, false);
  return __int_as_float(r);
}

__global__ __launch_bounds__(64) void dtw_kernel(const float* __restrict__ ap,
                                                 const float* __restrict__ bp,
                                                 float* __restrict__ out) {
  const int b = blockIdx.x;
  const int t = threadIdx.x;  // lane 0..63
  const float INF = INFINITY;

  // ap_pad[63 + i] = ap[b, i]; skirts zero-filled so no index clamping.
  __shared__ float ap_pad[L + 128];
  #pragma unroll
  for (int k = 0; k < (L + 128) / 64; ++k) {
    int idx = t + 64 * k;
    float v = 0.f;
    int src = idx - 63;
    if (src >= 0 && src < L) v = ap[b * L + src];
    ap_pad[idx] = v;
  }

  float bpv[16];
  float prev[16];
  #pragma unroll
  for (int m = 0; m < 16; ++m) {
    bpv[m] = bp[b * L + t * 16 + m];
    prev[m] = INF;
  }
  __syncthreads();

  const float* apl = &ap_pad[63 - t];  // apl[s] == ap[b, s - t] (0 in skirts)

  float right = INF;      // my x[15] of the row I last processed
  float prev_left = INF;  // R[i-1, 16t-1]
  float pf0 = apl[0];     // ap value for current step
  float pf1 = apl[1];     // ap value for next step

  // ---- Phase 1: ramp-up, s in [0,64). Lane-0 fixups + i>=0 predicate. ----
  for (int s = 0; s < 64; ++s) {
    float left = wave_shr1(right, INF);
    int i = s - t;
    if (t == 0) left = (i == 0) ? 0.f : INF;
    float apv = pf0;
    pf0 = pf1;
    pf1 = apl[s + 2];
    if (i >= 0) {
      float dprev = (t == 0) ? INF : prev_left;
      prev_left = left;
      float d[16];
      #pragma unroll
      for (int m = 0; m < 16; ++m) d[m] = apv - bpv[m];
      float x = left;
      #pragma unroll
      for (int m = 0; m < 16; ++m) {
        float cur = prev[m];
        float best = fminf(fminf(cur, dprev), x);
        x = __builtin_fmaf(d[m], d[m], best);
        dprev = cur;
        prev[m] = x;
      }
      right = x;
    }
  }

  // ---- Phase 2: steady state, s in [64,1024). All lanes active. ----------
  #pragma unroll 4
  for (int s = 64; s < L; ++s) {
    float left = wave_shr1(right, INF);  // lane 0 gets INF automatically
    float apv = pf0;
    pf0 = pf1;
    pf1 = apl[s + 2];
    float dprev = prev_left;  // lane 0: INF by invariant (prev_left=left=INF)
    prev_left = left;
    float d[16];
    #pragma unroll
    for (int m = 0; m < 16; ++m) d[m] = apv - bpv[m];
    float x = left;
    #pragma unroll
    for (int m = 0; m < 16; ++m) {
      float cur = prev[m];
      float best = fminf(fminf(cur, dprev), x);
      x = __builtin_fmaf(d[m], d[m], best);
      dprev = cur;
      prev[m] = x;
    }
    right = x;
  }

  // ---- Phase 3: drain, s in [1024,1087). i<L predicate only. -------------
  for (int s = L; s < L + 63; ++s) {
    float left = wave_shr1(right, INF);
    float apv = pf0;
    pf0 = pf1;
    pf1 = apl[s + 2];  // max index L+64+63 = 1151, in bounds
    int i = s - t;
    if (i < L) {
      float dprev = prev_left;
      prev_left = left;
      float d[16];
      #pragma unroll
      for (int m = 0; m < 16; ++m) d[m] = apv - bpv[m];
      float x = left;
      #pragma unroll
      for (int m = 0; m < 16; ++m) {
        float cur = prev[m];
        float best = fminf(fminf(cur, dprev), x);
        x = __builtin_fmaf(d[m], d[m], best);
        dprev = cur;
        prev[m] = x;
      }
      right = x;
    }
  }

  if (t == 63) out[b] = right;  // R[1023,1023]
}

extern "C" void kernel_launch(void* const* d_in, const int* in_sizes, int n_in,
                              void* d_out, int out_size, void* d_ws, size_t ws_size,
                              hipStream_t stream) {
  const float* a  = (const float*)d_in[0];
  const float* b  = (const float*)d_in[1];
  const float* W1 = (const float*)d_in[2];
  const float* b1 = (const float*)d_in[3];
  const float* W2 = (const float*)d_in[4];
  const float* b2 = (const float*)d_in[5];
  float* out = (float*)d_out;

  float* ap = (float*)d_ws;
  float* bp = ap + BATCH * L;

  proj_kernel<<<128, 256, 0, stream>>>(a, b, W1, b1, W2, b2, ap, bp);
  dtw_kernel<<<BATCH, 64, 0, stream>>>(ap, bp, out);
}